// Round 14
// baseline (377.700 us; speedup 1.0000x reference)
//
#include <hip/hip_runtime.h>

#define DEVINL __device__ __forceinline__

typedef __attribute__((ext_vector_type(8))) short short8;
typedef __attribute__((ext_vector_type(4))) short short4v;
typedef __attribute__((ext_vector_type(4))) float f32x4;
typedef const __attribute__((address_space(1))) void* gp1_t;
typedef __attribute__((address_space(3))) void* lp3_t;

static constexpr int Bsz = 2, T = 2048, C = 2048, H = 16, D = 128;
static constexpr int M = Bsz * T;          // 4096 rows
static constexpr float LOG2E = 1.44269504088896340736f;

DEVINL short f2bf(float f) {
  unsigned u = __builtin_bit_cast(unsigned, f);
  u += 0x7FFFu + ((u >> 16) & 1u);
  return (short)(u >> 16);
}
DEVINL float bf2f(short s) {
  unsigned u = ((unsigned)(unsigned short)s) << 16;
  return __builtin_bit_cast(float, u);
}
DEVINL void gload16(const void* g, void* l) {
  __builtin_amdgcn_global_load_lds((gp1_t)g, (lp3_t)l, 16, 0, 0);
}

// ---------------- x -> bf16 ----------------
__global__ __launch_bounds__(256) void convx_kernel(const float* __restrict__ in,
                                                    short* __restrict__ out) {
  int g = blockIdx.x * 256 + threadIdx.x;       // handles 4 floats
  float4 v = ((const float4*)in)[g];
  short4v o;
  o[0] = f2bf(v.x); o[1] = f2bf(v.y); o[2] = f2bf(v.z); o[3] = f2bf(v.w);
  ((short4v*)out)[g] = o;
}

// ---------------- all four W [K,N] fp32 -> WT [N,K] bf16 (one launch) ----------------
__global__ __launch_bounds__(256) void transw_kernel(const float* __restrict__ Wq,
                                                     const float* __restrict__ Wk,
                                                     const float* __restrict__ Wv,
                                                     const float* __restrict__ Wo,
                                                     short* __restrict__ WqkvT,
                                                     short* __restrict__ WoT) {
  __shared__ float ts[64][65];
  int bid = blockIdx.x;
  int w = bid >> 10; bid &= 1023;
  const float* W = (w == 0) ? Wq : (w == 1) ? Wk : (w == 2) ? Wv : Wo;
  short* WT = (w < 3) ? (WqkvT + (size_t)w * C * C) : WoT;
  int n0 = (bid & 31) << 6, k0 = (bid >> 5) << 6;
  int t = threadIdx.x;
#pragma unroll
  for (int i = 0; i < 16; ++i) {
    int li = i * 256 + t; int r = li >> 6, c = li & 63;
    ts[r][c] = W[(size_t)(k0 + r) * C + n0 + c];
  }
  __syncthreads();
#pragma unroll
  for (int i = 0; i < 16; ++i) {
    int li = i * 256 + t; int r = li >> 6, c = li & 63;   // r=n-local, c=k-local
    WT[(size_t)(n0 + r) * C + k0 + c] = f2bf(ts[c][r]);
  }
}

// ---------------- fused QKV GEMM + QK-norm: [M,2048] @ WqkvT[6144,2048]^T, BK=64 ----------------
// Column block (128 wide) == one head's full D=128 -> L2 norm computed in epilogue:
// per-lane nj-sum of squares, 4-step shfl_xor over l15 group, 1KB LDS exchange between
// the wn-paired waves (reuses As after final barrier), rsqrt; Q gets scale[h]*log2e.
__global__ __launch_bounds__(256) void gemm_qkv_kernel(
    const short* __restrict__ A, const short* __restrict__ Bt,
    const float* __restrict__ bq, const float* __restrict__ bk,
    const float* __restrict__ bv, const float* __restrict__ scale,
    short* __restrict__ Qb, short* __restrict__ Kb, short* __restrict__ Vtr) {
  constexpr int K = 2048;
  __shared__ short As[128 * 64];
  __shared__ short Bs[128 * 64];
  const int t = threadIdx.x;
  const int wid = t >> 6, lane = t & 63;
  const int l15 = lane & 15, lhi = lane >> 4;
  int bid = blockIdx.x;
  const int cpx = gridDim.x >> 3;               // XCD swizzle (nwg%8==0)
  bid = (bid & 7) * cpx + (bid >> 3);
  const int m0 = (bid / 48) << 7;
  const int n0 = (bid % 48) << 7;
  const int wm = (wid >> 1) << 6;
  const int wn = (wid & 1) << 6;

  const int srow = t >> 3;
  const int schk = (t & 7) ^ (srow & 7);
  const short* ga = A + (size_t)(m0 + srow) * K + schk * 8;
  const short* gb = Bt + (size_t)(n0 + srow) * K + schk * 8;
  short* lA = As + wid * 512;
  short* lB = Bs + wid * 512;

  f32x4 acc[4][4] = {};
  for (int k0 = 0; k0 < K; k0 += 64) {
#pragma unroll
    for (int i = 0; i < 4; ++i) {
      gload16(ga + (size_t)(i * 32) * K, lA + i * 2048);
      gload16(gb + (size_t)(i * 32) * K, lB + i * 2048);
    }
    ga += 64; gb += 64;
    __syncthreads();
#pragma unroll
    for (int kk = 0; kk < 2; ++kk) {
      const int cs = ((kk * 4 + lhi) ^ (l15 & 7)) * 8;
      short8 af[4], bf[4];
#pragma unroll
      for (int i = 0; i < 4; ++i)
        af[i] = *(const short8*)&As[(wm + i * 16 + l15) * 64 + cs];
#pragma unroll
      for (int j = 0; j < 4; ++j)
        bf[j] = *(const short8*)&Bs[(wn + j * 16 + l15) * 64 + cs];
#pragma unroll
      for (int i = 0; i < 4; ++i)
#pragma unroll
        for (int j = 0; j < 4; ++j)
          acc[i][j] = __builtin_amdgcn_mfma_f32_16x16x32_bf16(af[i], bf[j], acc[i][j], 0, 0, 0);
    }
    __syncthreads();
  }
  const int sel = n0 >> 11;                     // block-uniform: 0=Q,1=K,2=V
  const float* bias = (sel == 0) ? bq : (sel == 1) ? bk : bv;
  if (sel < 2) {
    short* Out = (sel == 0) ? Qb : Kb;
    const int hh = (n0 >> 7) & 15;
    const float qfac = scale[hh] * LOG2E;       // exp2-domain softmax factor (Q only)
#pragma unroll
    for (int i = 0; i < 4; ++i)
#pragma unroll
      for (int j = 0; j < 4; ++j) {
        int c2 = (n0 + wn + j * 16 + l15) & 2047;
        float bvv = bias[c2];
#pragma unroll
        for (int r = 0; r < 4; ++r) acc[i][j][r] += bvv;
      }
    float* nsum = (float*)As;                   // 4 waves x 64 floats = 1KB, safe after barrier
    f32x4 ps[4];
#pragma unroll
    for (int i = 0; i < 4; ++i) {
#pragma unroll
      for (int r = 0; r < 4; ++r)
        ps[i][r] = acc[i][0][r] * acc[i][0][r] + acc[i][1][r] * acc[i][1][r] +
                   acc[i][2][r] * acc[i][2][r] + acc[i][3][r] * acc[i][3][r];
#pragma unroll
      for (int off = 1; off < 16; off <<= 1)
#pragma unroll
        for (int r = 0; r < 4; ++r) ps[i][r] += __shfl_xor(ps[i][r], off, 64);
    }
    if (l15 == 0) {
#pragma unroll
      for (int i = 0; i < 4; ++i)
        *(f32x4*)&nsum[wid * 64 + i * 16 + lhi * 4] = ps[i];
    }
    __syncthreads();
    f32x4 facv[4];
#pragma unroll
    for (int i = 0; i < 4; ++i) {
      f32x4 po = *(const f32x4*)&nsum[(wid ^ 1) * 64 + i * 16 + lhi * 4];
#pragma unroll
      for (int r = 0; r < 4; ++r) {
        float fac = rsqrtf(ps[i][r] + po[r]);
        facv[i][r] = (sel == 0) ? fac * qfac : fac;
      }
    }
#pragma unroll
    for (int i = 0; i < 4; ++i) {
      int row = m0 + wm + i * 16 + lhi * 4;
#pragma unroll
      for (int j = 0; j < 4; ++j) {
        int c2 = (n0 + wn + j * 16 + l15) & 2047;
#pragma unroll
        for (int r = 0; r < 4; ++r)
          Out[(size_t)(row + r) * 2048 + c2] = f2bf(acc[i][j][r] * facv[i][r]);
      }
    }
  } else {
#pragma unroll
    for (int i = 0; i < 4; ++i) {
      int rowb = m0 + wm + i * 16 + lhi * 4;
      int bb = rowb >> 11, tt = rowb & 2047;
#pragma unroll
      for (int j = 0; j < 4; ++j) {
        int c2 = (n0 + wn + j * 16 + l15) & 2047;
        int hh = c2 >> 7, dd = c2 & 127;
        float bvv = bias[c2];
        short4v pv;
#pragma unroll
        for (int r = 0; r < 4; ++r) pv[r] = f2bf(acc[i][j][r] + bvv);
        *(short4v*)&Vtr[((size_t)((bb * 16 + hh) * 128 + dd)) * 2048 + tt] = pv;
      }
    }
  }
}

// ---------------- Wo GEMM: Cout[M,N] = A[M,K] @ Bt[N,K]^T + bias (fp32 out), BK=64 (R5-proven) ----------------
__global__ __launch_bounds__(256) void gemm_bt_kernel(
    const short* __restrict__ A, const short* __restrict__ Bt,
    const float* __restrict__ bias, float* __restrict__ Cout,
    int N, int K) {
  __shared__ short As[128 * 64];
  __shared__ short Bs[128 * 64];
  const int t = threadIdx.x;
  const int wid = t >> 6, lane = t & 63;
  const int l15 = lane & 15, lhi = lane >> 4;
  int bid = blockIdx.x;
  const int cpx = gridDim.x >> 3;
  bid = (bid & 7) * cpx + (bid >> 3);
  const int nbx = N >> 7;
  const int m0 = (bid / nbx) << 7;
  const int n0 = (bid % nbx) << 7;
  const int wm = (wid >> 1) << 6;
  const int wn = (wid & 1) << 6;

  const int srow = t >> 3;
  const int schk = (t & 7) ^ (srow & 7);
  const short* ga = A + (size_t)(m0 + srow) * K + schk * 8;
  const short* gb = Bt + (size_t)(n0 + srow) * K + schk * 8;
  short* lA = As + wid * 512;
  short* lB = Bs + wid * 512;

  f32x4 acc[4][4] = {};
  for (int k0 = 0; k0 < K; k0 += 64) {
#pragma unroll
    for (int i = 0; i < 4; ++i) {
      gload16(ga + (size_t)(i * 32) * K, lA + i * 2048);
      gload16(gb + (size_t)(i * 32) * K, lB + i * 2048);
    }
    ga += 64; gb += 64;
    __syncthreads();
#pragma unroll
    for (int kk = 0; kk < 2; ++kk) {
      const int cs = ((kk * 4 + lhi) ^ (l15 & 7)) * 8;
      short8 af[4], bf[4];
#pragma unroll
      for (int i = 0; i < 4; ++i)
        af[i] = *(const short8*)&As[(wm + i * 16 + l15) * 64 + cs];
#pragma unroll
      for (int j = 0; j < 4; ++j)
        bf[j] = *(const short8*)&Bs[(wn + j * 16 + l15) * 64 + cs];
#pragma unroll
      for (int i = 0; i < 4; ++i)
#pragma unroll
        for (int j = 0; j < 4; ++j)
          acc[i][j] = __builtin_amdgcn_mfma_f32_16x16x32_bf16(af[i], bf[j], acc[i][j], 0, 0, 0);
    }
    __syncthreads();
  }
#pragma unroll
  for (int i = 0; i < 4; ++i) {
    int row = m0 + wm + i * 16 + lhi * 4;
#pragma unroll
    for (int j = 0; j < 4; ++j) {
      int col = n0 + wn + j * 16 + l15;
      float bv = bias[col];
#pragma unroll
      for (int r = 0; r < 4; ++r)
        Cout[(size_t)(row + r) * N + col] = acc[i][j][r] + bv;
    }
  }
}

// ---------------- flash attention w/ ALiBi + causal, STATIC analytic row-max, exp2 domain ----------------
// R13 inner math byte-identical. Changes: (1) V read directly from global (L2-resident:
// each XCD's 4 bh = 4MB K+V = its L2) -> Vs LDS staging dropped; LDS 72->40KB -> 4 blocks/CU,
// __launch_bounds__(256,4) -> 16 waves/CU. (2) grid 1024 un-paired blocks; decode
// xcd=bid&7 (=bh&7, keeps L2 locality), v=(bid>>3)&31, g=bid>>8; bh=xcd|(g<<3);
// qt=(g&1)?v:31-v  -> under round-robin dispatch each CU's 4 blocks sum to 66 tiles.
__global__ __launch_bounds__(256, 4) void attn_kernel(const short* __restrict__ Qg,
                                                      const short* __restrict__ Kg,
                                                      const short* __restrict__ Vt,
                                                      const float* __restrict__ scale,
                                                      short* __restrict__ Ob) {
  __shared__ short Ks[2][64 * 128];   // [kv row][d], swizzled, 16KB each
  __shared__ short P[4][16 * 64];     // per-wave P tile
  const int t = threadIdx.x;
  const int wid = t >> 6, lane = t & 63;
  const int l15 = lane & 15, lhi = lane >> 4;
  const int bid = blockIdx.x;
  const int xcd = bid & 7;
  const int v = (bid >> 3) & 31;
  const int g = bid >> 8;                 // 0..3
  const int bh = xcd | (g << 3);
  const int qt = (g & 1) ? v : (31 - v);  // per-CU quads {31-v, v, 31-v, v}
  const int b = bh >> 4, h = bh & 15;
  const float slopeL = exp2f(-0.5f * (float)(h + 1)) * LOG2E;   // log2-domain slope
  const float sL = fabsf(scale[h]) * LOG2E;                     // log2-domain |scale|
  short* pw = &P[wid][0];
  const int sr16 = t >> 4, ss16 = t & 15;   // K tile: 16 rows x 16 chunks / issue

  const int ntiles = qt + 1;
  const int qrow = (qt << 6) + wid * 16;

  const short* qbase = Qg + (size_t)(b * T + qrow + l15) * C + h * D + lhi * 8;
  short8 qf[4];
#pragma unroll
  for (int ds = 0; ds < 4; ++ds) qf[ds] = *(const short8*)(qbase + ds * 32);

  // per-lane V base: row(d) = j*16 + l15, kv-chunk = ks*4 + lhi (no swizzle needed)
  const short* vlane = Vt + ((size_t)(bh * D + l15)) * T + lhi * 8;

  f32x4 o[8] = {};
  float lrow[4] = {0.f, 0.f, 0.f, 0.f};
  float mx[4];
#pragma unroll
  for (int r = 0; r < 4; ++r)
    mx[r] = sL + slopeL * (float)(qrow + lhi * 4 + r - (T - 1));

  // prologue: stage K tile 0 (source pre-swizzled, LDS linear)
#pragma unroll
  for (int i = 0; i < 4; ++i) {
    int r = i * 16 + sr16;
    int c = ss16 ^ (r & 7);
    gload16(Kg + (size_t)(b * T + r) * C + h * D + c * 8, &Ks[0][i * 2048 + wid * 512]);
  }
  __syncthreads();

  int cur = 0;
  for (int it = 0; it < ntiles; ++it) {
    const int k0 = it << 6;
    if (it + 1 < ntiles) {          // prefetch next K tile
      const int kn = k0 + 64;
#pragma unroll
      for (int i = 0; i < 4; ++i) {
        int r = i * 16 + sr16;
        int c = ss16 ^ (r & 7);
        gload16(Kg + (size_t)(b * T + kn + r) * C + h * D + c * 8,
                &Ks[cur ^ 1][i * 2048 + wid * 512]);
      }
    }
    const short* Ksb = &Ks[cur][0];

    // ---- QK^T from LDS ----
    f32x4 s[4] = {};
    __builtin_amdgcn_s_setprio(1);
#pragma unroll
    for (int nt = 0; nt < 4; ++nt) {
      int row = nt * 16 + l15;
#pragma unroll
      for (int ds = 0; ds < 4; ++ds) {
        int slot = (ds * 4 + lhi) ^ (l15 & 7);
        short8 kf = *(const short8*)&Ksb[row * 128 + slot * 8];
        s[nt] = __builtin_amdgcn_mfma_f32_16x16x32_bf16(qf[ds], kf, s[nt], 0, 0, 0);
      }
    }
    __builtin_amdgcn_s_setprio(0);

    // ---- ALiBi (all tiles) + causal mask (diagonal tile only) ----
#pragma unroll
    for (int nt = 0; nt < 4; ++nt) {
      int j = k0 + nt * 16 + l15;
      float al = slopeL * (float)(j - (T - 1));
#pragma unroll
      for (int r = 0; r < 4; ++r) s[nt][r] += al;
    }
    if (it == qt) {
#pragma unroll
      for (int nt = 0; nt < 4; ++nt) {
        int j = k0 + nt * 16 + l15;
#pragma unroll
        for (int r = 0; r < 4; ++r)
          if (j > qrow + lhi * 4 + r) s[nt][r] = -1e30f;
      }
    }
    // ---- exp2 vs static analytic max; accumulate lane-partial denominators ----
#pragma unroll
    for (int nt = 0; nt < 4; ++nt) {
#pragma unroll
      for (int r = 0; r < 4; ++r) {
        float e = exp2f(s[nt][r] - mx[r]);   // bare v_exp_f32
        lrow[r] += e;
        int prow = lhi * 4 + r, pcol = nt * 16 + l15;
        pw[prow * 64 + (pcol ^ ((prow & 7) << 3))] = f2bf(e);
      }
    }

    // ---- PV: P from per-wave LDS; V fragments direct from global (L2-resident) ----
    __builtin_amdgcn_s_setprio(1);
#pragma unroll
    for (int ks = 0; ks < 2; ++ks) {
      int c0 = ks * 32 + lhi * 8;
      short8 pf = *(const short8*)&pw[l15 * 64 + (c0 ^ ((l15 & 7) << 3))];
#pragma unroll
      for (int j = 0; j < 8; ++j) {
        short8 vf = *(const short8*)(vlane + (size_t)j * 16 * T + k0 + ks * 32);
        o[j] = __builtin_amdgcn_mfma_f32_16x16x32_bf16(pf, vf, o[j], 0, 0, 0);
      }
    }
    __builtin_amdgcn_s_setprio(0);

    __syncthreads();   // staging drained (compiler emits vmcnt(0) here); buffer swap
    cur ^= 1;
  }

  // ---- epilogue: one denominator reduce, then scale + store ----
#pragma unroll
  for (int off = 1; off < 16; off <<= 1)
#pragma unroll
    for (int r = 0; r < 4; ++r) lrow[r] += __shfl_xor(lrow[r], off, 64);
  float inv[4];
#pragma unroll
  for (int r = 0; r < 4; ++r) inv[r] = 1.f / lrow[r];
  short* ob = Ob + (size_t)(b * T + qrow + lhi * 4) * C + h * D;
#pragma unroll
  for (int j = 0; j < 8; ++j)
#pragma unroll
    for (int r = 0; r < 4; ++r)
      ob[(size_t)r * C + j * 16 + l15] = f2bf(o[j][r] * inv[r]);
}

extern "C" void kernel_launch(void* const* d_in, const int* in_sizes, int n_in,
                              void* d_out, int out_size, void* d_ws, size_t ws_size,
                              hipStream_t stream) {
  const float* x  = (const float*)d_in[0];
  const float* Wq = (const float*)d_in[1];
  const float* bq = (const float*)d_in[2];
  const float* Wk = (const float*)d_in[3];
  const float* bk = (const float*)d_in[4];
  const float* Wv = (const float*)d_in[5];
  const float* bv = (const float*)d_in[6];
  const float* Wo = (const float*)d_in[7];
  const float* bo = (const float*)d_in[8];
  const float* scale = (const float*)d_in[9];
  float* out = (float*)d_out;

  short* ws = (short*)d_ws;
  const size_t SZ_ROWS = (size_t)M * C;
  const size_t SZ_W = (size_t)C * C;
  short* xb     = ws;
  short* WqkvT  = xb + SZ_ROWS;          // [6144, 2048]
  short* WoT    = WqkvT + 3 * SZ_W;
  short* Qb     = WoT + SZ_W;
  short* Kb     = Qb + SZ_ROWS;
  short* Vt     = Kb + SZ_ROWS;          // [B,H,D,T]
  short* Ob     = Vt + SZ_ROWS;

  convx_kernel<<<(M * C) / (256 * 4), 256, 0, stream>>>(x, xb);
  transw_kernel<<<4096, 256, 0, stream>>>(Wq, Wk, Wv, Wo, WqkvT, WoT);

  gemm_qkv_kernel<<<1536, 256, 0, stream>>>(xb, WqkvT, bq, bk, bv, scale, Qb, Kb, Vt);

  attn_kernel<<<1024, 256, 0, stream>>>(Qb, Kb, Vt, scale, Ob);

  gemm_bt_kernel<<<512, 256, 0, stream>>>(Ob, WoT, bo, out, C, C);
}

// Round 15
// 257.377 us; speedup vs baseline: 1.4675x; 1.4675x over previous
//
#include <hip/hip_runtime.h>

#define DEVINL __device__ __forceinline__

typedef __attribute__((ext_vector_type(8))) short short8;
typedef __attribute__((ext_vector_type(4))) short short4v;
typedef __attribute__((ext_vector_type(4))) float f32x4;
typedef const __attribute__((address_space(1))) void* gp1_t;
typedef __attribute__((address_space(3))) void* lp3_t;

static constexpr int Bsz = 2, T = 2048, C = 2048, H = 16, D = 128;
static constexpr int M = Bsz * T;          // 4096 rows
static constexpr float LOG2E = 1.44269504088896340736f;

DEVINL short f2bf(float f) {
  unsigned u = __builtin_bit_cast(unsigned, f);
  u += 0x7FFFu + ((u >> 16) & 1u);
  return (short)(u >> 16);
}
DEVINL float bf2f(short s) {
  unsigned u = ((unsigned)(unsigned short)s) << 16;
  return __builtin_bit_cast(float, u);
}
DEVINL void gload16(const void* g, void* l) {
  __builtin_amdgcn_global_load_lds((gp1_t)g, (lp3_t)l, 16, 0, 0);
}

// ---------------- x -> bf16 ----------------
__global__ __launch_bounds__(256) void convx_kernel(const float* __restrict__ in,
                                                    short* __restrict__ out) {
  int g = blockIdx.x * 256 + threadIdx.x;       // handles 4 floats
  float4 v = ((const float4*)in)[g];
  short4v o;
  o[0] = f2bf(v.x); o[1] = f2bf(v.y); o[2] = f2bf(v.z); o[3] = f2bf(v.w);
  ((short4v*)out)[g] = o;
}

// ---------------- all four W [K,N] fp32 -> WT [N,K] bf16 (one launch) ----------------
__global__ __launch_bounds__(256) void transw_kernel(const float* __restrict__ Wq,
                                                     const float* __restrict__ Wk,
                                                     const float* __restrict__ Wv,
                                                     const float* __restrict__ Wo,
                                                     short* __restrict__ WqkvT,
                                                     short* __restrict__ WoT) {
  __shared__ float ts[64][65];
  int bid = blockIdx.x;
  int w = bid >> 10; bid &= 1023;
  const float* W = (w == 0) ? Wq : (w == 1) ? Wk : (w == 2) ? Wv : Wo;
  short* WT = (w < 3) ? (WqkvT + (size_t)w * C * C) : WoT;
  int n0 = (bid & 31) << 6, k0 = (bid >> 5) << 6;
  int t = threadIdx.x;
#pragma unroll
  for (int i = 0; i < 16; ++i) {
    int li = i * 256 + t; int r = li >> 6, c = li & 63;
    ts[r][c] = W[(size_t)(k0 + r) * C + n0 + c];
  }
  __syncthreads();
#pragma unroll
  for (int i = 0; i < 16; ++i) {
    int li = i * 256 + t; int r = li >> 6, c = li & 63;   // r=n-local, c=k-local
    WT[(size_t)(n0 + r) * C + k0 + c] = f2bf(ts[c][r]);
  }
}

// ---------------- fused QKV GEMM + QK-norm: [M,2048] @ WqkvT[6144,2048]^T, BK=64 ----------------
// Column block (128 wide) == one head's full D=128 -> L2 norm computed in epilogue:
// per-lane nj-sum of squares, 4-step shfl_xor over l15 group, 1KB LDS exchange between
// the wn-paired waves (reuses As after final barrier), rsqrt; Q gets scale[h]*log2e.
__global__ __launch_bounds__(256) void gemm_qkv_kernel(
    const short* __restrict__ A, const short* __restrict__ Bt,
    const float* __restrict__ bq, const float* __restrict__ bk,
    const float* __restrict__ bv, const float* __restrict__ scale,
    short* __restrict__ Qb, short* __restrict__ Kb, short* __restrict__ Vtr) {
  constexpr int K = 2048;
  __shared__ short As[128 * 64];
  __shared__ short Bs[128 * 64];
  const int t = threadIdx.x;
  const int wid = t >> 6, lane = t & 63;
  const int l15 = lane & 15, lhi = lane >> 4;
  int bid = blockIdx.x;
  const int cpx = gridDim.x >> 3;               // XCD swizzle (nwg%8==0)
  bid = (bid & 7) * cpx + (bid >> 3);
  const int m0 = (bid / 48) << 7;
  const int n0 = (bid % 48) << 7;
  const int wm = (wid >> 1) << 6;
  const int wn = (wid & 1) << 6;

  const int srow = t >> 3;
  const int schk = (t & 7) ^ (srow & 7);
  const short* ga = A + (size_t)(m0 + srow) * K + schk * 8;
  const short* gb = Bt + (size_t)(n0 + srow) * K + schk * 8;
  short* lA = As + wid * 512;
  short* lB = Bs + wid * 512;

  f32x4 acc[4][4] = {};
  for (int k0 = 0; k0 < K; k0 += 64) {
#pragma unroll
    for (int i = 0; i < 4; ++i) {
      gload16(ga + (size_t)(i * 32) * K, lA + i * 2048);
      gload16(gb + (size_t)(i * 32) * K, lB + i * 2048);
    }
    ga += 64; gb += 64;
    __syncthreads();
#pragma unroll
    for (int kk = 0; kk < 2; ++kk) {
      const int cs = ((kk * 4 + lhi) ^ (l15 & 7)) * 8;
      short8 af[4], bf[4];
#pragma unroll
      for (int i = 0; i < 4; ++i)
        af[i] = *(const short8*)&As[(wm + i * 16 + l15) * 64 + cs];
#pragma unroll
      for (int j = 0; j < 4; ++j)
        bf[j] = *(const short8*)&Bs[(wn + j * 16 + l15) * 64 + cs];
#pragma unroll
      for (int i = 0; i < 4; ++i)
#pragma unroll
        for (int j = 0; j < 4; ++j)
          acc[i][j] = __builtin_amdgcn_mfma_f32_16x16x32_bf16(af[i], bf[j], acc[i][j], 0, 0, 0);
    }
    __syncthreads();
  }
  const int sel = n0 >> 11;                     // block-uniform: 0=Q,1=K,2=V
  const float* bias = (sel == 0) ? bq : (sel == 1) ? bk : bv;
  if (sel < 2) {
    short* Out = (sel == 0) ? Qb : Kb;
    const int hh = (n0 >> 7) & 15;
    const float qfac = scale[hh] * LOG2E;       // exp2-domain softmax factor (Q only)
#pragma unroll
    for (int i = 0; i < 4; ++i)
#pragma unroll
      for (int j = 0; j < 4; ++j) {
        int c2 = (n0 + wn + j * 16 + l15) & 2047;
        float bvv = bias[c2];
#pragma unroll
        for (int r = 0; r < 4; ++r) acc[i][j][r] += bvv;
      }
    float* nsum = (float*)As;                   // 4 waves x 64 floats = 1KB, safe after barrier
    f32x4 ps[4];
#pragma unroll
    for (int i = 0; i < 4; ++i) {
#pragma unroll
      for (int r = 0; r < 4; ++r)
        ps[i][r] = acc[i][0][r] * acc[i][0][r] + acc[i][1][r] * acc[i][1][r] +
                   acc[i][2][r] * acc[i][2][r] + acc[i][3][r] * acc[i][3][r];
#pragma unroll
      for (int off = 1; off < 16; off <<= 1)
#pragma unroll
        for (int r = 0; r < 4; ++r) ps[i][r] += __shfl_xor(ps[i][r], off, 64);
    }
    if (l15 == 0) {
#pragma unroll
      for (int i = 0; i < 4; ++i)
        *(f32x4*)&nsum[wid * 64 + i * 16 + lhi * 4] = ps[i];
    }
    __syncthreads();
    f32x4 facv[4];
#pragma unroll
    for (int i = 0; i < 4; ++i) {
      f32x4 po = *(const f32x4*)&nsum[(wid ^ 1) * 64 + i * 16 + lhi * 4];
#pragma unroll
      for (int r = 0; r < 4; ++r) {
        float fac = rsqrtf(ps[i][r] + po[r]);
        facv[i][r] = (sel == 0) ? fac * qfac : fac;
      }
    }
#pragma unroll
    for (int i = 0; i < 4; ++i) {
      int row = m0 + wm + i * 16 + lhi * 4;
#pragma unroll
      for (int j = 0; j < 4; ++j) {
        int c2 = (n0 + wn + j * 16 + l15) & 2047;
#pragma unroll
        for (int r = 0; r < 4; ++r)
          Out[(size_t)(row + r) * 2048 + c2] = f2bf(acc[i][j][r] * facv[i][r]);
      }
    }
  } else {
#pragma unroll
    for (int i = 0; i < 4; ++i) {
      int rowb = m0 + wm + i * 16 + lhi * 4;
      int bb = rowb >> 11, tt = rowb & 2047;
#pragma unroll
      for (int j = 0; j < 4; ++j) {
        int c2 = (n0 + wn + j * 16 + l15) & 2047;
        int hh = c2 >> 7, dd = c2 & 127;
        float bvv = bias[c2];
        short4v pv;
#pragma unroll
        for (int r = 0; r < 4; ++r) pv[r] = f2bf(acc[i][j][r] + bvv);
        *(short4v*)&Vtr[((size_t)((bb * 16 + hh) * 128 + dd)) * 2048 + tt] = pv;
      }
    }
  }
}

// ---------------- Wo GEMM: Cout[M,N] = A[M,K] @ Bt[N,K]^T + bias (fp32 out), BK=64 (R5-proven) ----------------
__global__ __launch_bounds__(256) void gemm_bt_kernel(
    const short* __restrict__ A, const short* __restrict__ Bt,
    const float* __restrict__ bias, float* __restrict__ Cout,
    int N, int K) {
  __shared__ short As[128 * 64];
  __shared__ short Bs[128 * 64];
  const int t = threadIdx.x;
  const int wid = t >> 6, lane = t & 63;
  const int l15 = lane & 15, lhi = lane >> 4;
  int bid = blockIdx.x;
  const int cpx = gridDim.x >> 3;
  bid = (bid & 7) * cpx + (bid >> 3);
  const int nbx = N >> 7;
  const int m0 = (bid / nbx) << 7;
  const int n0 = (bid % nbx) << 7;
  const int wm = (wid >> 1) << 6;
  const int wn = (wid & 1) << 6;

  const int srow = t >> 3;
  const int schk = (t & 7) ^ (srow & 7);
  const short* ga = A + (size_t)(m0 + srow) * K + schk * 8;
  const short* gb = Bt + (size_t)(n0 + srow) * K + schk * 8;
  short* lA = As + wid * 512;
  short* lB = Bs + wid * 512;

  f32x4 acc[4][4] = {};
  for (int k0 = 0; k0 < K; k0 += 64) {
#pragma unroll
    for (int i = 0; i < 4; ++i) {
      gload16(ga + (size_t)(i * 32) * K, lA + i * 2048);
      gload16(gb + (size_t)(i * 32) * K, lB + i * 2048);
    }
    ga += 64; gb += 64;
    __syncthreads();
#pragma unroll
    for (int kk = 0; kk < 2; ++kk) {
      const int cs = ((kk * 4 + lhi) ^ (l15 & 7)) * 8;
      short8 af[4], bf[4];
#pragma unroll
      for (int i = 0; i < 4; ++i)
        af[i] = *(const short8*)&As[(wm + i * 16 + l15) * 64 + cs];
#pragma unroll
      for (int j = 0; j < 4; ++j)
        bf[j] = *(const short8*)&Bs[(wn + j * 16 + l15) * 64 + cs];
#pragma unroll
      for (int i = 0; i < 4; ++i)
#pragma unroll
        for (int j = 0; j < 4; ++j)
          acc[i][j] = __builtin_amdgcn_mfma_f32_16x16x32_bf16(af[i], bf[j], acc[i][j], 0, 0, 0);
    }
    __syncthreads();
  }
#pragma unroll
  for (int i = 0; i < 4; ++i) {
    int row = m0 + wm + i * 16 + lhi * 4;
#pragma unroll
    for (int j = 0; j < 4; ++j) {
      int col = n0 + wn + j * 16 + l15;
      float bv = bias[col];
#pragma unroll
      for (int r = 0; r < 4; ++r)
        Cout[(size_t)(row + r) * N + col] = acc[i][j][r] + bv;
    }
  }
}

// ---------------- flash attention w/ ALiBi + causal, STATIC analytic row-max, exp2 domain ----------------
// R9-proven structure. All softmax quantities carry log2(e) (folded into Q-scale in the
// QKV epilogue, ALiBi slope, static max bound) -> inner op is bare exp2f (one v_exp_f32).
__global__ __launch_bounds__(256) void attn_kernel(const short* __restrict__ Qg,
                                                   const short* __restrict__ Kg,
                                                   const short* __restrict__ Vt,
                                                   const float* __restrict__ scale,
                                                   short* __restrict__ Ob) {
  __shared__ short Ks[2][64 * 128];   // [kv row][d], swizzled, 16KB each
  __shared__ short Vs[2][128 * 64];   // [d][kv col], swizzled, 16KB each
  __shared__ short P[4][16 * 64];     // per-wave P tile
  const int t = threadIdx.x;
  const int wid = t >> 6, lane = t & 63;
  const int l15 = lane & 15, lhi = lane >> 4;
  const int bid = blockIdx.x;
  const int bh = bid & 31;            // XCD-locality: bid%8 == bh%8
  const int pairIdx = bid >> 5;
  const int b = bh >> 4, h = bh & 15;
  const float slopeL = exp2f(-0.5f * (float)(h + 1)) * LOG2E;   // log2-domain slope
  const float sL = fabsf(scale[h]) * LOG2E;                     // log2-domain |scale|
  short* pw = &P[wid][0];
  const int sr16 = t >> 4, ss16 = t & 15;   // K tile: 16 rows x 16 chunks / issue
  const int sr32 = t >> 3, ss8 = t & 7;     // V tile: 32 rows x 8 chunks / issue

  for (int phase = 0; phase < 2; ++phase) {
    const int qt = phase ? pairIdx : (31 - pairIdx);   // long phase first
    const int ntiles = qt + 1;
    const int qrow = (qt << 6) + wid * 16;

    const short* qbase = Qg + (size_t)(b * T + qrow + l15) * C + h * D + lhi * 8;
    short8 qf[4];
#pragma unroll
    for (int ds = 0; ds < 4; ++ds) qf[ds] = *(const short8*)(qbase + ds * 32);

    f32x4 o[8] = {};
    float lrow[4] = {0.f, 0.f, 0.f, 0.f};
    float mx[4];
#pragma unroll
    for (int r = 0; r < 4; ++r)
      mx[r] = sL + slopeL * (float)(qrow + lhi * 4 + r - (T - 1));

#pragma unroll
    for (int i = 0; i < 4; ++i) {
      int r = i * 16 + sr16;
      int c = ss16 ^ (r & 7);
      gload16(Kg + (size_t)(b * T + r) * C + h * D + c * 8, &Ks[0][i * 2048 + wid * 512]);
    }
#pragma unroll
    for (int i = 0; i < 4; ++i) {
      int r = i * 32 + sr32;
      int c = ss8 ^ (r & 7);
      gload16(Vt + (size_t)(bh * D + r) * T + c * 8, &Vs[0][i * 2048 + wid * 512]);
    }
    __syncthreads();

    int cur = 0;
    for (int it = 0; it < ntiles; ++it) {
      const int k0 = it << 6;
      if (it + 1 < ntiles) {
        const int kn = k0 + 64;
#pragma unroll
        for (int i = 0; i < 4; ++i) {
          int r = i * 16 + sr16;
          int c = ss16 ^ (r & 7);
          gload16(Kg + (size_t)(b * T + kn + r) * C + h * D + c * 8,
                  &Ks[cur ^ 1][i * 2048 + wid * 512]);
        }
#pragma unroll
        for (int i = 0; i < 4; ++i) {
          int r = i * 32 + sr32;
          int c = ss8 ^ (r & 7);
          gload16(Vt + (size_t)(bh * D + r) * T + kn + c * 8,
                  &Vs[cur ^ 1][i * 2048 + wid * 512]);
        }
      }
      const short* Ksb = &Ks[cur][0];
      const short* Vsb = &Vs[cur][0];

      f32x4 s[4] = {};
      __builtin_amdgcn_s_setprio(1);
#pragma unroll
      for (int nt = 0; nt < 4; ++nt) {
        int row = nt * 16 + l15;
#pragma unroll
        for (int ds = 0; ds < 4; ++ds) {
          int slot = (ds * 4 + lhi) ^ (l15 & 7);
          short8 kf = *(const short8*)&Ksb[row * 128 + slot * 8];
          s[nt] = __builtin_amdgcn_mfma_f32_16x16x32_bf16(qf[ds], kf, s[nt], 0, 0, 0);
        }
      }
      __builtin_amdgcn_s_setprio(0);

#pragma unroll
      for (int nt = 0; nt < 4; ++nt) {
        int j = k0 + nt * 16 + l15;
        float al = slopeL * (float)(j - (T - 1));
#pragma unroll
        for (int r = 0; r < 4; ++r) s[nt][r] += al;
      }
      if (it == qt) {
#pragma unroll
        for (int nt = 0; nt < 4; ++nt) {
          int j = k0 + nt * 16 + l15;
#pragma unroll
          for (int r = 0; r < 4; ++r)
            if (j > qrow + lhi * 4 + r) s[nt][r] = -1e30f;
        }
      }
#pragma unroll
      for (int nt = 0; nt < 4; ++nt) {
#pragma unroll
        for (int r = 0; r < 4; ++r) {
          float e = exp2f(s[nt][r] - mx[r]);   // bare v_exp_f32
          lrow[r] += e;
          int prow = lhi * 4 + r, pcol = nt * 16 + l15;
          pw[prow * 64 + (pcol ^ ((prow & 7) << 3))] = f2bf(e);
        }
      }

      __builtin_amdgcn_s_setprio(1);
#pragma unroll
      for (int ks = 0; ks < 2; ++ks) {
        int c0 = ks * 32 + lhi * 8;
        short8 pf = *(const short8*)&pw[l15 * 64 + (c0 ^ ((l15 & 7) << 3))];
#pragma unroll
        for (int j = 0; j < 8; ++j) {
          int row = j * 16 + l15;
          int slot = (ks * 4 + lhi) ^ (l15 & 7);
          short8 vf = *(const short8*)&Vsb[row * 64 + slot * 8];
          o[j] = __builtin_amdgcn_mfma_f32_16x16x32_bf16(pf, vf, o[j], 0, 0, 0);
        }
      }
      __builtin_amdgcn_s_setprio(0);

      __syncthreads();
      cur ^= 1;
    }

#pragma unroll
    for (int off = 1; off < 16; off <<= 1)
#pragma unroll
      for (int r = 0; r < 4; ++r) lrow[r] += __shfl_xor(lrow[r], off, 64);
    float inv[4];
#pragma unroll
    for (int r = 0; r < 4; ++r) inv[r] = 1.f / lrow[r];
    short* ob = Ob + (size_t)(b * T + qrow + lhi * 4) * C + h * D;
#pragma unroll
    for (int j = 0; j < 8; ++j)
#pragma unroll
      for (int r = 0; r < 4; ++r)
        ob[(size_t)r * C + j * 16 + l15] = f2bf(o[j][r] * inv[r]);
  }
}

extern "C" void kernel_launch(void* const* d_in, const int* in_sizes, int n_in,
                              void* d_out, int out_size, void* d_ws, size_t ws_size,
                              hipStream_t stream) {
  const float* x  = (const float*)d_in[0];
  const float* Wq = (const float*)d_in[1];
  const float* bq = (const float*)d_in[2];
  const float* Wk = (const float*)d_in[3];
  const float* bk = (const float*)d_in[4];
  const float* Wv = (const float*)d_in[5];
  const float* bv = (const float*)d_in[6];
  const float* Wo = (const float*)d_in[7];
  const float* bo = (const float*)d_in[8];
  const float* scale = (const float*)d_in[9];
  float* out = (float*)d_out;

  short* ws = (short*)d_ws;
  const size_t SZ_ROWS = (size_t)M * C;
  const size_t SZ_W = (size_t)C * C;
  short* xb     = ws;
  short* WqkvT  = xb + SZ_ROWS;          // [6144, 2048]
  short* WoT    = WqkvT + 3 * SZ_W;
  short* Qb     = WoT + SZ_W;
  short* Kb     = Qb + SZ_ROWS;
  short* Vt     = Kb + SZ_ROWS;          // [B,H,D,T]
  short* Ob     = Vt + SZ_ROWS;

  convx_kernel<<<(M * C) / (256 * 4), 256, 0, stream>>>(x, xb);
  transw_kernel<<<4096, 256, 0, stream>>>(Wq, Wk, Wv, Wo, WqkvT, WoT);

  gemm_qkv_kernel<<<1536, 256, 0, stream>>>(xb, WqkvT, bq, bk, bv, scale, Qb, Kb, Vt);

  attn_kernel<<<512, 256, 0, stream>>>(Qb, Kb, Vt, scale, Ob);

  gemm_bt_kernel<<<512, 256, 0, stream>>>(Ob, WoT, bo, out, C, C);
}